// Round 10
// baseline (438.782 us; speedup 1.0000x reference)
//
#include <hip/hip_runtime.h>
#include <hip/hip_bf16.h>
#include <math.h>

#define HW 4096
#define EPSV 1e-5f

typedef unsigned short ushort;
typedef __attribute__((ext_vector_type(8))) short bf16x8;
typedef __attribute__((ext_vector_type(4))) float f32x4;

__device__ inline ushort f2bf(float f) {
    __hip_bfloat16 h = __float2bfloat16(f);
    return *reinterpret_cast<ushort*>(&h);
}
__device__ inline float bf2f(ushort u) {
    unsigned int v = ((unsigned int)u) << 16;
    return __uint_as_float(v);
}

// ---------------------------------------------------------------------------
// fp32 [b][C][4096] -> bf16 channel-last [b][4096][C], LDS transpose.
// ---------------------------------------------------------------------------
template<int C>
__global__ __launch_bounds__(256) void to_chlast_bf16(
    const float* __restrict__ src, ushort* __restrict__ dst)
{
    const int b = blockIdx.z, c0 = blockIdx.y * 64, p0 = blockIdx.x * 64;
    const int tid = threadIdx.x;
    __shared__ float sT[64][65];
    for (int i = tid; i < 4096; i += 256) {
        const int ch = i >> 6, px = i & 63;
        sT[ch][px] = src[(size_t)(b * C + c0 + ch) * HW + p0 + px];
    }
    __syncthreads();
    const int px = tid >> 2, seg = tid & 3;
    ushort tmp[16];
    #pragma unroll
    for (int j = 0; j < 16; ++j) tmp[j] = f2bf(sT[seg * 16 + j][px]);
    ushort* d = dst + (size_t)(b * HW + p0 + px) * C + c0 + seg * 16;
    *(uint4*)d = *(uint4*)&tmp[0];
    *(uint4*)(d + 8) = *(uint4*)&tmp[8];
}

// ---------------------------------------------------------------------------
// Pack 3x3 weights [co][ci][3][3] fp32 -> [tap][ci/32][co][ci32] bf16.
// ---------------------------------------------------------------------------
template<int CIN, int COUT>
__global__ __launch_bounds__(256) void pack_w3x3(
    const float* __restrict__ w, ushort* __restrict__ wpk)
{
    const int idx = blockIdx.x * 256 + threadIdx.x;
    constexpr int total = 9 * (CIN / 32) * COUT * 32;
    if (idx >= total) return;
    const int ci_in = idx & 31;
    int rest = idx >> 5;
    const int co = rest % COUT; rest /= COUT;
    const int cc = rest % (CIN / 32);
    const int tap = rest / (CIN / 32);
    wpk[idx] = f2bf(w[((size_t)co * CIN + cc * 32 + ci_in) * 9 + tap]);
}

// ---------------------------------------------------------------------------
// Pack 1x1 weights [co][stride] fp32 -> [co][K] bf16 (first K columns).
// ---------------------------------------------------------------------------
__global__ __launch_bounds__(256) void pack_w1x1(
    const float* __restrict__ w, ushort* __restrict__ o,
    int K, int stride, int total)
{
    const int idx = blockIdx.x * 256 + threadIdx.x;
    if (idx >= total) return;
    const int co = idx / K, k = idx - co * K;
    o[idx] = f2bf(w[(size_t)co * stride + k]);
}

// ---------------------------------------------------------------------------
// MFMA implicit-GEMM 3x3 conv + BN + PReLU.  ROWS output rows per block.
// Weights are read as fragments STRAIGHT FROM GLOBAL (coalesced 1 KB/wave,
// L2-resident) — LDS only stages the input pixels, padded to 40 (2-way max).
// ---------------------------------------------------------------------------
template<int CIN, int COUT, int COTILE, int DIL, int ROWS>
__global__ __launch_bounds__(256) void conv3x3_mfma(
    const ushort* __restrict__ xin,   // [b][64][64][CIN] bf16
    const ushort* __restrict__ wpk,   // [9][CIN/32][COUT][32] bf16
    const float* __restrict__ bias, const float* __restrict__ bng,
    const float* __restrict__ bnb, const float* __restrict__ bnm,
    const float* __restrict__ bnv, const float* __restrict__ al,
    float* __restrict__ out)
{
    constexpr int HR = ROWS + 2 * DIL;
    constexpr int NC = 64 + 2 * DIL;
    constexpr int MT = COTILE / 16;
    constexpr int WPR = 4 / ROWS;
    constexpr int NT = ROWS;
    constexpr int SAS = 40;             // padded row stride (20 banks -> 2-way max)

    const int tid = threadIdx.x;
    const int wave = tid >> 6, lane = tid & 63;
    const int l15 = lane & 15, quad = lane >> 4;
    const int b = blockIdx.z;
    const int co0 = blockIdx.y * COTILE;
    const int h0 = blockIdx.x * ROWS;
    const int row = wave / WPR;
    const int ntbase = (wave % WPR) * NT;

    __shared__ __align__(16) ushort sA[HR * NC * SAS];
    __shared__ float sScale[COTILE], sShift[COTILE];

    if (tid < COTILE) {
        const int co = co0 + tid;
        const float sc = bng[co] * rsqrtf(bnv[co] + EPSV);
        sScale[tid] = sc;
        sShift[tid] = (bias[co] - bnm[co]) * sc + bnb[co];
    }

    f32x4 acc[MT][NT];
    #pragma unroll
    for (int mt = 0; mt < MT; ++mt)
        #pragma unroll
        for (int nt = 0; nt < NT; ++nt) acc[mt][nt] = (f32x4){0.f, 0.f, 0.f, 0.f};

    #pragma unroll 1
    for (int cc = 0; cc < CIN / 32; ++cc) {
        __syncthreads();
        constexpr int NA = HR * NC * 4;
        for (int i = tid; i < NA; i += 256) {
            const int p = i >> 2, seg = i & 3;
            const int r = p / NC, c = p - r * NC;
            const int grow = h0 - DIL + r, gcol = c - DIL;
            uint4 val = {0u, 0u, 0u, 0u};
            if (grow >= 0 && grow < 64 && gcol >= 0 && gcol < 64)
                val = *(const uint4*)&xin[((size_t)(b * 64 + grow) * 64 + gcol) * CIN
                                          + cc * 32 + seg * 8];
            *(uint4*)&sA[p * SAS + seg * 8] = val;
        }
        __syncthreads();

        #pragma unroll
        for (int ty = 0; ty < 3; ++ty)
            #pragma unroll
            for (int tx = 0; tx < 3; ++tx) {
                const int tap = ty * 3 + tx;
                bf16x8 aw[MT];
                #pragma unroll
                for (int mt = 0; mt < MT; ++mt)
                    aw[mt] = *(const bf16x8*)&wpk[
                        ((size_t)(tap * (CIN / 32) + cc) * COUT + co0 + mt * 16 + l15) * 32
                        + quad * 8];
                const int rl = row + ty * DIL;
                #pragma unroll
                for (int nt = 0; nt < NT; ++nt) {
                    const int cl = (ntbase + nt) * 16 + l15 + tx * DIL;
                    const bf16x8 bp = *(const bf16x8*)&sA[(rl * NC + cl) * SAS + quad * 8];
                    #pragma unroll
                    for (int mt = 0; mt < MT; ++mt)
                        acc[mt][nt] = __builtin_amdgcn_mfma_f32_16x16x32_bf16(
                            aw[mt], bp, acc[mt][nt], 0, 0, 0);
                }
            }
    }

    const float a = al[0];
    #pragma unroll
    for (int mt = 0; mt < MT; ++mt)
        #pragma unroll
        for (int rr = 0; rr < 4; ++rr) {
            const int col = mt * 16 + quad * 4 + rr;
            const float sc = sScale[col], sh = sShift[col];
            const int co = co0 + col;
            #pragma unroll
            for (int nt = 0; nt < NT; ++nt) {
                float t = acc[mt][nt][rr] * sc + sh;
                t = t >= 0.f ? t : a * t;
                out[((size_t)(b * COUT + co) * 64 + h0 + row) * 64
                    + (ntbase + nt) * 16 + l15] = t;
            }
        }
}

// ---------------------------------------------------------------------------
// MFMA 1x1 conv on channel-last bf16 input, frags straight from global.
// ---------------------------------------------------------------------------
template<int CIN, int COUT, bool BNACT, int OMODE>
__global__ __launch_bounds__(256) void gemm1x1_cl(
    const ushort* __restrict__ xin,   // [16384][CIN] bf16
    const ushort* __restrict__ wbf,   // [COUT][CIN] bf16
    const float* __restrict__ bias, const float* __restrict__ bng,
    const float* __restrict__ bnb, const float* __restrict__ bnm,
    const float* __restrict__ bnv, const float* __restrict__ al,
    const float* __restrict__ ebias, void* __restrict__ outv,
    int ostride, int ocol)
{
    const int tid = threadIdx.x;
    const int wave = tid >> 6, lane = tid & 63;
    const int l15 = lane & 15, quad = lane >> 4;
    const int pix0 = blockIdx.x * 128 + wave * 32;
    const int co0 = blockIdx.y * 64;

    f32x4 acc[4][2];
    #pragma unroll
    for (int mt = 0; mt < 4; ++mt)
        #pragma unroll
        for (int nt = 0; nt < 2; ++nt) acc[mt][nt] = (f32x4){0.f, 0.f, 0.f, 0.f};

    #pragma unroll 2
    for (int cc = 0; cc < CIN / 32; ++cc) {
        bf16x8 aw[4], bp[2];
        #pragma unroll
        for (int mt = 0; mt < 4; ++mt)
            aw[mt] = *(const bf16x8*)&wbf[(size_t)(co0 + mt * 16 + l15) * CIN + cc * 32 + quad * 8];
        #pragma unroll
        for (int nt = 0; nt < 2; ++nt)
            bp[nt] = *(const bf16x8*)&xin[(size_t)(pix0 + nt * 16 + l15) * CIN + cc * 32 + quad * 8];
        #pragma unroll
        for (int mt = 0; mt < 4; ++mt)
            #pragma unroll
            for (int nt = 0; nt < 2; ++nt)
                acc[mt][nt] = __builtin_amdgcn_mfma_f32_16x16x32_bf16(
                    aw[mt], bp[nt], acc[mt][nt], 0, 0, 0);
    }

    const int bI = pix0 >> 12;
    const float a = BNACT ? al[0] : 0.f;

    if (OMODE == 0) {
        float* out = (float*)outv;
        #pragma unroll
        for (int mt = 0; mt < 4; ++mt)
            #pragma unroll
            for (int r = 0; r < 4; ++r) {
                const int co = co0 + mt * 16 + quad * 4 + r;
                float bb = bias[co];
                if (ebias) bb += ebias[bI * COUT + co];
                float scale = 1.f, shift = bb;
                if (BNACT) {
                    scale = bng[co] * rsqrtf(bnv[co] + EPSV);
                    shift = bb * scale + (bnb[co] - bnm[co] * scale);
                }
                #pragma unroll
                for (int nt = 0; nt < 2; ++nt) {
                    float t = acc[mt][nt][r] * scale + shift;
                    if (BNACT) t = t >= 0.f ? t : a * t;
                    out[((size_t)(bI * COUT + co)) * HW + (pix0 & 4095) + nt * 16 + l15] = t;
                }
            }
    } else {
        __shared__ ushort sT[4][32][68];
        #pragma unroll
        for (int mt = 0; mt < 4; ++mt)
            #pragma unroll
            for (int r = 0; r < 4; ++r) {
                const int co = co0 + mt * 16 + quad * 4 + r;
                float bb = bias[co];
                float scale = 1.f, shift = bb;
                if (BNACT) {
                    scale = bng[co] * rsqrtf(bnv[co] + EPSV);
                    shift = bb * scale + (bnb[co] - bnm[co] * scale);
                }
                #pragma unroll
                for (int nt = 0; nt < 2; ++nt) {
                    float t = acc[mt][nt][r] * scale + shift;
                    if (BNACT) t = t >= 0.f ? t : a * t;
                    sT[wave][nt * 16 + l15][mt * 16 + quad * 4 + r] = f2bf(t);
                }
            }
        __syncthreads();
        const int p = lane >> 1, half = lane & 1;
        ushort* out = (ushort*)outv;
        #pragma unroll
        for (int seg = 0; seg < 4; ++seg) {
            uint2 a0 = *(uint2*)&sT[wave][p][half * 32 + seg * 8];
            uint2 a1 = *(uint2*)&sT[wave][p][half * 32 + seg * 8 + 4];
            uint4 vv = {a0.x, a0.y, a1.x, a1.y};
            *(uint4*)&out[(size_t)(pix0 + p) * ostride + ocol + co0 + half * 32 + seg * 8] = vv;
        }
    }
}

// ---------------------------------------------------------------------------
// Generic fp32 1x1 conv (kept for v).  OUTBF16: write bf16.
// ---------------------------------------------------------------------------
template<int CIN, bool BNACT, bool OUTBF16>
__global__ __launch_bounds__(256) void conv1x1_kernel(
    const float* __restrict__ in0,
    const float* __restrict__ wgt, int wstride, int COUT,
    const float* __restrict__ bias, const float* __restrict__ al,
    void* __restrict__ outv)
{
    const int tid = threadIdx.x;
    const int b = blockIdx.z, co0 = blockIdx.y * 64, p0 = blockIdx.x * 64;
    const int cg = tid >> 4, pg = tid & 15;
    const int c0l = cg * 4, w0 = pg * 4;

    __shared__ __align__(16) float sIn[16 * 64];
    __shared__ __align__(16) float sW[16 * 68];

    float acc[4][4] = {};

    for (int cc = 0; cc < CIN; cc += 16) {
        {
            int i = tid;
            #pragma unroll
            for (int it = 0; it < 4; ++it, i += 256) {
                const int px = i & 63, ci = i >> 6;
                sIn[ci * 64 + px] = in0[(size_t)(b * CIN + cc + ci) * HW + p0 + px];
            }
            i = tid;
            #pragma unroll
            for (int it = 0; it < 4; ++it, i += 256) {
                const int ci = i & 15, co = i >> 4;
                sW[ci * 68 + co] = wgt[(co0 + co) * wstride + cc + ci];
            }
        }
        __syncthreads();
        #pragma unroll
        for (int ci = 0; ci < 16; ++ci) {
            const float4 iv = *(const float4*)&sIn[ci * 64 + w0];
            const float4 wv = *(const float4*)&sW[ci * 68 + c0l];
            const float ia[4] = {iv.x, iv.y, iv.z, iv.w};
            const float wa[4] = {wv.x, wv.y, wv.z, wv.w};
            #pragma unroll
            for (int i2 = 0; i2 < 4; ++i2)
                #pragma unroll
                for (int j = 0; j < 4; ++j)
                    acc[i2][j] = fmaf(wa[i2], ia[j], acc[i2][j]);
        }
        __syncthreads();
    }

    const float a = BNACT ? al[0] : 0.f;
    #pragma unroll
    for (int i2 = 0; i2 < 4; ++i2) {
        const int co = co0 + c0l + i2;
        const float shift = bias[co];
        float r[4];
        #pragma unroll
        for (int j = 0; j < 4; ++j) {
            float t = acc[i2][j] + shift;
            r[j] = (BNACT && t < 0.f) ? a * t : t;
        }
        const size_t base = (size_t)(b * COUT + co) * HW + p0 + w0;
        if (OUTBF16) {
            ushort* out = (ushort*)outv;
            #pragma unroll
            for (int j = 0; j < 4; ++j) out[base + j] = f2bf(r[j]);
        } else {
            float* out = (float*)outv;
            *(float4*)&out[base] = make_float4(r[0], r[1], r[2], r[3]);
        }
    }
}

// ---------------------------------------------------------------------------
// q & k 1x1 convs (128 -> 16 each) -> packed bf16 [b][4096][32] (16 ch + 16 zero)
// ---------------------------------------------------------------------------
__global__ __launch_bounds__(256) void qk_kernel(
    const float* __restrict__ c2g, const float* __restrict__ qw,
    const float* __restrict__ qb2, const float* __restrict__ kw,
    const float* __restrict__ kb2, ushort* __restrict__ qpack,
    ushort* __restrict__ kpack)
{
    const int b = blockIdx.y, p0 = blockIdx.x * 64, tid = threadIdx.x;
    __shared__ float sC[128][64];
    __shared__ float sWq[16][128];
    __shared__ float sWk[16][128];
    for (int i = tid; i < 8192; i += 256) {
        const int px = i & 63, ci = i >> 6;
        sC[ci][px] = c2g[(size_t)(b * 128 + ci) * HW + p0 + px];
    }
    for (int i = tid; i < 2048; i += 256) {
        const int ci = i & 127, co = i >> 7;
        sWq[co][ci] = qw[co * 128 + ci];
        sWk[co][ci] = kw[co * 128 + ci];
    }
    __syncthreads();
    const int px = tid & 63, grp = tid >> 6;
    const int co0 = (grp & 1) * 8;
    const bool isK = grp >= 2;
    const float* sWp = isK ? &sWk[0][0] : &sWq[0][0];
    float acc[8] = {};
    for (int ci = 0; ci < 128; ++ci) {
        const float xv = sC[ci][px];
        #pragma unroll
        for (int j = 0; j < 8; ++j)
            acc[j] = fmaf(sWp[(co0 + j) * 128 + ci], xv, acc[j]);
    }
    const float* bsrc = isK ? kb2 : qb2;
    ushort* osrc = isK ? kpack : qpack;
    const size_t base = (size_t)(b * 4096 + p0 + px) * 32;
    #pragma unroll
    for (int j = 0; j < 8; ++j) {
        osrc[base + co0 + j] = f2bf(acc[j] + bsrc[co0 + j]);
        osrc[base + 16 + co0 + j] = 0;
    }
}

// ---------------------------------------------------------------------------
// Two-pass flash attention, V staged through block-shared LDS.
// Grid: (32 nblk, 8 msplit, 4 batch).
// ---------------------------------------------------------------------------
__global__ __launch_bounds__(256) void attn_flash(
    const ushort* __restrict__ qpack,
    const ushort* __restrict__ kpack,
    const ushort* __restrict__ vpackT,
    ushort* __restrict__ opart,       // [b][8j][4096n][128c] bf16
    float* __restrict__ Mpart,        // [b][8j][4096n]
    float* __restrict__ Spart)
{
    const int tid = threadIdx.x;
    const int wave = tid >> 6, lane = tid & 63;
    const int l15 = lane & 15, quad = lane >> 4;
    const int b = blockIdx.z, j = blockIdx.y;
    const int n0w = blockIdx.x * 128 + wave * 32;
    const int m_begin = j * 512;

    __shared__ __align__(16) ushort sV[2][128][40];     // [buf][c][32m + pad]
    __shared__ __align__(16) ushort sP[4][2][16][40];   // wave-private [g][n][32m + pad]

    const bf16x8 bq0 = *(const bf16x8*)(qpack + ((size_t)(b * 4096 + n0w + l15) * 32 + quad * 8));
    const bf16x8 bq1 = *(const bf16x8*)(qpack + ((size_t)(b * 4096 + n0w + 16 + l15) * 32 + quad * 8));
    const f32x4 z = {0.f, 0.f, 0.f, 0.f};

    // ---- pass 1: exact row max, in-register only ----
    float runM0 = -3e30f, runM1 = -3e30f;
    #pragma unroll 2
    for (int t = 0; t < 8; ++t) {
        const int m0 = m_begin + t * 64;
        #pragma unroll
        for (int ms = 0; ms < 4; ++ms) {
            const bf16x8 ak = *(const bf16x8*)(
                kpack + ((size_t)(b * 4096 + m0 + ms * 16 + l15) * 32 + quad * 8));
            const f32x4 s0 = __builtin_amdgcn_mfma_f32_16x16x32_bf16(ak, bq0, z, 0, 0, 0);
            const f32x4 s1 = __builtin_amdgcn_mfma_f32_16x16x32_bf16(ak, bq1, z, 0, 0, 0);
            runM0 = fmaxf(runM0, fmaxf(fmaxf(s0[0], s0[1]), fmaxf(s0[2], s0[3])));
            runM1 = fmaxf(runM1, fmaxf(fmaxf(s1[0], s1[1]), fmaxf(s1[2], s1[3])));
        }
    }
    runM0 = fmaxf(runM0, __shfl_xor(runM0, 16));
    runM0 = fmaxf(runM0, __shfl_xor(runM0, 32));
    runM1 = fmaxf(runM1, __shfl_xor(runM1, 16));
    runM1 = fmaxf(runM1, __shfl_xor(runM1, 32));
    const float Ms0 = runM0 * 1.44269504f;
    const float Ms1 = runM1 * 1.44269504f;

    // ---- pass 2: m-tile 32, V via LDS ----
    float runS0 = 0.f, runS1 = 0.f;
    f32x4 oacc0[8], oacc1[8];
    #pragma unroll
    for (int cs = 0; cs < 8; ++cs) {
        oacc0[cs] = (f32x4){0.f, 0.f, 0.f, 0.f};
        oacc1[cs] = (f32x4){0.f, 0.f, 0.f, 0.f};
    }

    const int stc = tid >> 1, stseg = tid & 1;

    {
        uint4 v0 = *(const uint4*)&vpackT[(size_t)(b * 128 + stc) * HW + m_begin + stseg * 16];
        uint4 v1 = *(const uint4*)&vpackT[(size_t)(b * 128 + stc) * HW + m_begin + stseg * 16 + 8];
        *(uint4*)&sV[0][stc][stseg * 16] = v0;
        *(uint4*)&sV[0][stc][stseg * 16 + 8] = v1;
    }
    __syncthreads();

    #pragma unroll 1
    for (int t = 0; t < 16; ++t) {
        const int m0 = m_begin + t * 32;
        const int buf = t & 1;
        uint4 nv0, nv1;
        const bool more = (t + 1 < 16);
        if (more) {
            const size_t nb = (size_t)(b * 128 + stc) * HW + m0 + 32 + stseg * 16;
            nv0 = *(const uint4*)&vpackT[nb];
            nv1 = *(const uint4*)&vpackT[nb + 8];
        }
        f32x4 s0[2], s1[2];
        #pragma unroll
        for (int ms = 0; ms < 2; ++ms) {
            const bf16x8 ak = *(const bf16x8*)(
                kpack + ((size_t)(b * 4096 + m0 + ms * 16 + l15) * 32 + quad * 8));
            s0[ms] = __builtin_amdgcn_mfma_f32_16x16x32_bf16(ak, bq0, z, 0, 0, 0);
            s1[ms] = __builtin_amdgcn_mfma_f32_16x16x32_bf16(ak, bq1, z, 0, 0, 0);
        }
        #pragma unroll
        for (int ms = 0; ms < 2; ++ms) {
            float p0[4], p1[4];
            #pragma unroll
            for (int r = 0; r < 4; ++r) {
                p0[r] = __builtin_amdgcn_exp2f(fmaf(s0[ms][r], 1.44269504f, -Ms0));
                p1[r] = __builtin_amdgcn_exp2f(fmaf(s1[ms][r], 1.44269504f, -Ms1));
                runS0 += p0[r];
                runS1 += p1[r];
            }
            ushort4 u0, u1;
            u0.x = f2bf(p0[0]); u0.y = f2bf(p0[1]); u0.z = f2bf(p0[2]); u0.w = f2bf(p0[3]);
            u1.x = f2bf(p1[0]); u1.y = f2bf(p1[1]); u1.z = f2bf(p1[2]); u1.w = f2bf(p1[3]);
            *(uint2*)&sP[wave][0][l15][ms * 16 + quad * 4] = *(uint2*)&u0;
            *(uint2*)&sP[wave][1][l15][ms * 16 + quad * 4] = *(uint2*)&u1;
        }
        asm volatile("s_waitcnt lgkmcnt(0)" ::: "memory");
        const bf16x8 ap0 = *(const bf16x8*)&sP[wave][0][l15][quad * 8];
        const bf16x8 ap1 = *(const bf16x8*)&sP[wave][1][l15][quad * 8];
        #pragma unroll
        for (int cs = 0; cs < 8; ++cs) {
            const bf16x8 bv = *(const bf16x8*)&sV[buf][cs * 16 + l15][quad * 8];
            oacc0[cs] = __builtin_amdgcn_mfma_f32_16x16x32_bf16(ap0, bv, oacc0[cs], 0, 0, 0);
            oacc1[cs] = __builtin_amdgcn_mfma_f32_16x16x32_bf16(ap1, bv, oacc1[cs], 0, 0, 0);
        }
        if (more) {
            *(uint4*)&sV[buf ^ 1][stc][stseg * 16] = nv0;
            *(uint4*)&sV[buf ^ 1][stc][stseg * 16 + 8] = nv1;
            __syncthreads();
        }
    }

    runS0 += __shfl_xor(runS0, 16);
    runS0 += __shfl_xor(runS0, 32);
    runS1 += __shfl_xor(runS1, 16);
    runS1 += __shfl_xor(runS1, 32);
    if (lane < 32) {
        const float Mv = (lane < 16) ? runM0 : runM1;
        const float Sv = (lane < 16) ? runS0 : runS1;
        const int n = n0w + ((lane < 16) ? 0 : 16) + l15;
        Mpart[((size_t)b * 8 + j) * 4096 + n] = Mv;
        Spart[((size_t)b * 8 + j) * 4096 + n] = Sv;
    }
    #pragma unroll
    for (int cs = 0; cs < 8; ++cs)
        #pragma unroll
        for (int r = 0; r < 4; ++r) {
            const int n = n0w + quad * 4 + r;
            opart[(((size_t)b * 8 + j) * 4096 + n) * 128 + cs * 16 + l15] = f2bf(oacc0[cs][r]);
            opart[(((size_t)b * 8 + j) * 4096 + n + 16) * 128 + cs * 16 + l15] = f2bf(oacc1[cs][r]);
        }
}

// ---------------------------------------------------------------------------
// Combine 8 m-split partials, normalize, fuse gamma2*O + c2 -> catb[:,128:256]
// ---------------------------------------------------------------------------
__global__ __launch_bounds__(256) void attn_combine(
    const ushort* __restrict__ opart, const float* __restrict__ Mpart,
    const float* __restrict__ Spart, const float* __restrict__ c2g,
    const float* __restrict__ gamma2, ushort* __restrict__ catb)
{
    const int b = blockIdx.y, n0 = blockIdx.x * 32, tid = threadIdx.x;
    __shared__ float sC2[128][33];
    __shared__ float sWj[8][32];
    if (tid < 32) {
        const int n = n0 + tid;
        float Mj[8], Sj[8];
        #pragma unroll
        for (int j = 0; j < 8; ++j) {
            Mj[j] = Mpart[((size_t)b * 8 + j) * 4096 + n];
            Sj[j] = Spart[((size_t)b * 8 + j) * 4096 + n];
        }
        float M = -3e30f;
        #pragma unroll
        for (int j = 0; j < 8; ++j) M = fmaxf(M, Mj[j]);
        float St = 0.f, e[8];
        #pragma unroll
        for (int j = 0; j < 8; ++j) { e[j] = __expf(Mj[j] - M); St += Sj[j] * e[j]; }
        const float inv = 1.0f / St;
        #pragma unroll
        for (int j = 0; j < 8; ++j) sWj[j][tid] = e[j] * inv;
    }
    #pragma unroll
    for (int e = 0; e < 16; ++e) {
        const int idx = tid + e * 256;
        const int c = idx >> 5, n = idx & 31;
        sC2[c][n] = c2g[(size_t)(b * 128 + c) * HW + n0 + n];
    }
    __syncthreads();
    const float g2 = gamma2[0];
    #pragma unroll
    for (int e = 0; e < 16; ++e) {
        const int idx = tid + e * 256;
        const int n = idx >> 7, c = idx & 127;
        float s = 0.f;
        #pragma unroll
        for (int j = 0; j < 8; ++j)
            s += bf2f(opart[(((size_t)b * 8 + j) * 4096 + n0 + n) * 128 + c]) * sWj[j][n];
        catb[(size_t)(b * 4096 + n0 + n) * 256 + 128 + c] = f2bf(fmaf(g2, s, sC2[c][n]));
    }
}

// ---------------------------------------------------------------------------
__global__ __launch_bounds__(256) void pool_kernel(
    const float* __restrict__ xp, float* __restrict__ pool)
{
    const int c = blockIdx.x, b = blockIdx.y, tid = threadIdx.x;
    const float4* row = (const float4*)(xp + (size_t)(b * 256 + c) * HW);
    float s = 0.f;
    #pragma unroll 4
    for (int i = tid; i < 1024; i += 256) {
        const float4 t = row[i];
        s += t.x + t.y + t.z + t.w;
    }
    __shared__ float red[256];
    red[tid] = s; __syncthreads();
    for (int st = 128; st > 0; st >>= 1) {
        if (tid < st) red[tid] += red[tid + st];
        __syncthreads();
    }
    if (tid == 0) pool[b * 256 + c] = red[0] * (1.0f / 4096.0f);
}

// ---------------------------------------------------------------------------
__global__ __launch_bounds__(256) void c3_fbias_kernel(
    const float* __restrict__ pool, const float* __restrict__ c3w,
    const float* __restrict__ c3b, const float* __restrict__ bng,
    const float* __restrict__ bnb, const float* __restrict__ bnm,
    const float* __restrict__ bnv, const float* __restrict__ al,
    const float* __restrict__ fw, float* __restrict__ fbias)
{
    const int b = blockIdx.x, tid = threadIdx.x;
    __shared__ float sp[256];
    __shared__ float sc3[128];
    sp[tid] = pool[b * 256 + tid];
    __syncthreads();
    if (tid < 128) {
        float acc = c3b[tid];
        for (int ci = 0; ci < 256; ++ci) acc = fmaf(c3w[tid * 256 + ci], sp[ci], acc);
        const float scale = bng[tid] * rsqrtf(bnv[tid] + EPSV);
        float t = (acc - bnm[tid]) * scale + bnb[tid];
        const float a = al[0];
        sc3[tid] = t >= 0.f ? t : a * t;
    }
    __syncthreads();
    float f = 0.f;
    for (int j = 0; j < 128; ++j) f = fmaf(fw[tid * 384 + 256 + j], sc3[j], f);
    fbias[b * 256 + tid] = f;
}

// ---------------------------------------------------------------------------
extern "C" void kernel_launch(void* const* d_in, const int* in_sizes, int n_in,
                              void* d_out, int out_size, void* d_ws, size_t ws_size,
                              hipStream_t stream)
{
    const float* x     = (const float*)d_in[0];
    const float* dc_w  = (const float*)d_in[1];
    const float* dc_b  = (const float*)d_in[2];
    const float* dc_g  = (const float*)d_in[3];
    const float* dc_bt = (const float*)d_in[4];
    const float* dc_m  = (const float*)d_in[5];
    const float* dc_v  = (const float*)d_in[6];
    const float* dc_a  = (const float*)d_in[7];
    const float* c1_w  = (const float*)d_in[8];
    const float* c1_b  = (const float*)d_in[9];
    const float* c1_g  = (const float*)d_in[10];
    const float* c1_bt = (const float*)d_in[11];
    const float* c1_m  = (const float*)d_in[12];
    const float* c1_v  = (const float*)d_in[13];
    const float* c1_a  = (const float*)d_in[14];
    const float* c2_w  = (const float*)d_in[15];
    const float* c2_b  = (const float*)d_in[16];
    const float* c2_g  = (const float*)d_in[17];
    const float* c2_bt = (const float*)d_in[18];
    const float* c2_m  = (const float*)d_in[19];
    const float* c2_v  = (const float*)d_in[20];
    const float* c2_a  = (const float*)d_in[21];
    const float* q_w   = (const float*)d_in[22];
    const float* q_b   = (const float*)d_in[23];
    const float* k_w   = (const float*)d_in[24];
    const float* k_b   = (const float*)d_in[25];
    const float* v_w   = (const float*)d_in[26];
    const float* v_b   = (const float*)d_in[27];
    const float* gamma2= (const float*)d_in[28];
    const float* c3_w  = (const float*)d_in[29];
    const float* c3_b  = (const float*)d_in[30];
    const float* c3_g  = (const float*)d_in[31];
    const float* c3_bt = (const float*)d_in[32];
    const float* c3_m  = (const float*)d_in[33];
    const float* c3_v  = (const float*)d_in[34];
    const float* c3_a  = (const float*)d_in[35];
    const float* f_w   = (const float*)d_in[36];
    const float* f_b   = (const float*)d_in[37];
    const float* f_g   = (const float*)d_in[38];
    const float* f_bt  = (const float*)d_in[39];
    const float* f_m   = (const float*)d_in[40];
    const float* f_v   = (const float*)d_in[41];
    const float* f_a   = (const float*)d_in[42];

    // ---- workspace layout (opart overlaps xp+xbf, both dead pre-attention) ----
    char* base = (char*)d_ws;
    ushort* opart = (ushort*)base;                       // [4,8,4096,128] = 33.5 MB
    float*  xp    = (float*)base;                        //  [4,256,4096] fp32 (early)
    ushort* xbf   = (ushort*)(base + 16777216);          //  [4,4096,512] bf16 (early)
    float*  c2b   = (float*)(base + 33554432);           // [4,128,4096] fp32
    ushort* catb  = (ushort*)(base + 41943040);          // [4,4096,256] bf16
    ushort* xpbf  = (ushort*)(base + 58720256);          // [4,4096,256] bf16
    ushort* qpk   = (ushort*)(base + 67108864);          // [4,4096,32]
    ushort* kpk   = (ushort*)(base + 68157440);
    ushort* vbh   = (ushort*)(base + 69206016);          // [4,128,4096]
    ushort* wdcp  = (ushort*)(base + 73400320);          // [9,16,256,32]
    ushort* wc2p  = (ushort*)(base + 75759616);          // [9,8,128,32]
    ushort* wc1b  = (ushort*)(base + 76349440);          // [128,256]
    ushort* wfb   = (ushort*)(base + 76414976);          // [256,256]
    float*  poolb = (float*)(base + 76546048);           // 1024
    float*  fbb   = (float*)(base + 76550144);           // 1024
    float*  Mpart = (float*)(base + 76554240);           // [4,8,4096]
    float*  Spart = (float*)(base + 77078528);           // [4,8,4096]

    // 0. packs + x -> channel-last bf16
    pack_w3x3<512, 256><<<dim3((9*16*256*32 + 255)/256), 256, 0, stream>>>(dc_w, wdcp);
    pack_w3x3<256, 128><<<dim3((9*8*128*32 + 255)/256), 256, 0, stream>>>(c2_w, wc2p);
    pack_w1x1<<<dim3((32768 + 255)/256), 256, 0, stream>>>(c1_w, wc1b, 256, 256, 32768);
    pack_w1x1<<<dim3((65536 + 255)/256), 256, 0, stream>>>(f_w, wfb, 256, 384, 65536);
    to_chlast_bf16<512><<<dim3(64, 8, 4), 256, 0, stream>>>(x, xbf);
    // 1. down_conv 3x3 512->256 (MFMA, weights from global)
    conv3x3_mfma<512, 256, 64, 1, 2><<<dim3(32, 4, 4), 256, 0, stream>>>(
        xbf, wdcp, dc_b, dc_g, dc_bt, dc_m, dc_v, dc_a, xp);
    // 1b. xp -> channel-last bf16; pool + c3 fbias (xp dies here)
    to_chlast_bf16<256><<<dim3(64, 4, 4), 256, 0, stream>>>(xp, xpbf);
    pool_kernel<<<dim3(256, 4), 256, 0, stream>>>(xp, poolb);
    c3_fbias_kernel<<<dim3(4), 256, 0, stream>>>(
        poolb, c3_w, c3_b, c3_g, c3_bt, c3_m, c3_v, c3_a, f_w, fbb);
    // 2. branch1 1x1 (MFMA) -> catb cols 0..127
    gemm1x1_cl<256, 128, true, 1><<<dim3(128, 2), 256, 0, stream>>>(
        xpbf, wc1b, c1_b, c1_g, c1_bt, c1_m, c1_v, c1_a, nullptr, catb, 256, 0);
    // 3. branch2 dilated 3x3 (MFMA, weights from global)
    conv3x3_mfma<256, 128, 32, 2, 2><<<dim3(32, 4, 4), 256, 0, stream>>>(
        xpbf, wc2p, c2_b, c2_g, c2_bt, c2_m, c2_v, c2_a, c2b);
    // 4. q,k
    qk_kernel<<<dim3(64, 4), 256, 0, stream>>>(c2b, q_w, q_b, k_w, k_b, qpk, kpk);
    // 5. v -> bf16 [c][m]
    conv1x1_kernel<128, false, true><<<dim3(64, 2, 4), 256, 0, stream>>>(
        c2b, v_w, 128, 128, v_b, nullptr, vbh);
    // 6. flash attention (V via LDS) + combine
    attn_flash<<<dim3(32, 8, 4), 256, 0, stream>>>(qpk, kpk, vbh, opart, Mpart, Spart);
    attn_combine<<<dim3(128, 4), 256, 0, stream>>>(opart, Mpart, Spart, c2b, gamma2, catb);
    // 7. fuse conv (MFMA, K=256) -> d_out
    gemm1x1_cl<256, 256, true, 0><<<dim3(128, 4), 256, 0, stream>>>(
        catb, wfb, f_b, f_g, f_bt, f_m, f_v, f_a, fbb, (float*)d_out, 0, 0);
}

// Round 11
// 433.237 us; speedup vs baseline: 1.0128x; 1.0128x over previous
//
#include <hip/hip_runtime.h>
#include <hip/hip_bf16.h>
#include <math.h>

#define HW 4096
#define EPSV 1e-5f

typedef unsigned short ushort;
typedef __attribute__((ext_vector_type(8))) short bf16x8;
typedef __attribute__((ext_vector_type(4))) float f32x4;

__device__ inline ushort f2bf(float f) {
    __hip_bfloat16 h = __float2bfloat16(f);
    return *reinterpret_cast<ushort*>(&h);
}
__device__ inline float bf2f(ushort u) {
    unsigned int v = ((unsigned int)u) << 16;
    return __uint_as_float(v);
}

// ---------------------------------------------------------------------------
// fp32 [b][C][4096] -> bf16 channel-last [b][4096][C], LDS transpose.
// (used for the input x only)
// ---------------------------------------------------------------------------
template<int C>
__global__ __launch_bounds__(256) void to_chlast_bf16(
    const float* __restrict__ src, ushort* __restrict__ dst)
{
    const int b = blockIdx.z, c0 = blockIdx.y * 64, p0 = blockIdx.x * 64;
    const int tid = threadIdx.x;
    __shared__ float sT[64][65];
    for (int i = tid; i < 4096; i += 256) {
        const int ch = i >> 6, px = i & 63;
        sT[ch][px] = src[(size_t)(b * C + c0 + ch) * HW + p0 + px];
    }
    __syncthreads();
    const int px = tid >> 2, seg = tid & 3;
    ushort tmp[16];
    #pragma unroll
    for (int j = 0; j < 16; ++j) tmp[j] = f2bf(sT[seg * 16 + j][px]);
    ushort* d = dst + (size_t)(b * HW + p0 + px) * C + c0 + seg * 16;
    *(uint4*)d = *(uint4*)&tmp[0];
    *(uint4*)(d + 8) = *(uint4*)&tmp[8];
}

// ---------------------------------------------------------------------------
// dc combine: p[ks][b][256][4096] (x2, fp32) -> add -> BN+PReLU -> bf16
// channel-last [b][4096][256] via LDS transpose.
// ---------------------------------------------------------------------------
__global__ __launch_bounds__(256) void dc_combine(
    const float* __restrict__ part,     // [8][256][4096] (ks*4+b major)
    const float* __restrict__ bias, const float* __restrict__ bng,
    const float* __restrict__ bnb, const float* __restrict__ bnm,
    const float* __restrict__ bnv, const float* __restrict__ al,
    ushort* __restrict__ dst)
{
    const int b = blockIdx.z, c0 = blockIdx.y * 64, p0 = blockIdx.x * 64;
    const int tid = threadIdx.x;
    __shared__ float sT[64][65];
    __shared__ float sSc[64], sSh[64];
    if (tid < 64) {
        const int c = c0 + tid;
        const float sc = bng[c] * rsqrtf(bnv[c] + EPSV);
        sSc[tid] = sc;
        sSh[tid] = (bias[c] - bnm[c]) * sc + bnb[c];
    }
    __syncthreads();
    const float a = al[0];
    for (int i = tid; i < 4096; i += 256) {
        const int ch = i >> 6, px = i & 63;
        const size_t i0 = (size_t)(b * 256 + c0 + ch) * HW + p0 + px;
        float v = part[i0] + part[i0 + (size_t)4 * 256 * HW];
        float t = v * sSc[ch] + sSh[ch];
        sT[ch][px] = t >= 0.f ? t : a * t;
    }
    __syncthreads();
    const int px = tid >> 2, seg = tid & 3;
    ushort tmp[16];
    #pragma unroll
    for (int j = 0; j < 16; ++j) tmp[j] = f2bf(sT[seg * 16 + j][px]);
    ushort* d = dst + (size_t)(b * HW + p0 + px) * 256 + c0 + seg * 16;
    *(uint4*)d = *(uint4*)&tmp[0];
    *(uint4*)(d + 8) = *(uint4*)&tmp[8];
}

// ---------------------------------------------------------------------------
// c2 combine: p[ks][b][128][4096] -> add -> BN+PReLU -> c2b fp32 ch-first.
// Grid (4, 128, 4); thread handles 4 px (float4).
// ---------------------------------------------------------------------------
__global__ __launch_bounds__(256) void c2_combine(
    const float* __restrict__ part,     // [8][128][4096]
    const float* __restrict__ bias, const float* __restrict__ bng,
    const float* __restrict__ bnb, const float* __restrict__ bnm,
    const float* __restrict__ bnv, const float* __restrict__ al,
    float* __restrict__ out)
{
    const int c = blockIdx.y, b = blockIdx.z;
    const int px = blockIdx.x * 1024 + threadIdx.x * 4;
    const float sc = bng[c] * rsqrtf(bnv[c] + EPSV);
    const float sh = (bias[c] - bnm[c]) * sc + bnb[c];
    const float a = al[0];
    const size_t i0 = (size_t)(b * 128 + c) * HW + px;
    const float4 v0 = *(const float4*)&part[i0];
    const float4 v1 = *(const float4*)&part[i0 + (size_t)4 * 128 * HW];
    float4 o;
    float t;
    t = (v0.x + v1.x) * sc + sh; o.x = t >= 0.f ? t : a * t;
    t = (v0.y + v1.y) * sc + sh; o.y = t >= 0.f ? t : a * t;
    t = (v0.z + v1.z) * sc + sh; o.z = t >= 0.f ? t : a * t;
    t = (v0.w + v1.w) * sc + sh; o.w = t >= 0.f ? t : a * t;
    *(float4*)&out[(size_t)(b * 128 + c) * HW + px] = o;
}

// ---------------------------------------------------------------------------
// Pack 3x3 weights [co][ci][3][3] fp32 -> [tap][ci/32][co][ci32] bf16.
// ---------------------------------------------------------------------------
template<int CIN, int COUT>
__global__ __launch_bounds__(256) void pack_w3x3(
    const float* __restrict__ w, ushort* __restrict__ wpk)
{
    const int idx = blockIdx.x * 256 + threadIdx.x;
    constexpr int total = 9 * (CIN / 32) * COUT * 32;
    if (idx >= total) return;
    const int ci_in = idx & 31;
    int rest = idx >> 5;
    const int co = rest % COUT; rest /= COUT;
    const int cc = rest % (CIN / 32);
    const int tap = rest / (CIN / 32);
    wpk[idx] = f2bf(w[((size_t)co * CIN + cc * 32 + ci_in) * 9 + tap]);
}

// ---------------------------------------------------------------------------
// Pack 1x1 weights [co][stride] fp32 -> [co][K] bf16 (first K columns).
// ---------------------------------------------------------------------------
__global__ __launch_bounds__(256) void pack_w1x1(
    const float* __restrict__ w, ushort* __restrict__ o,
    int K, int stride, int total)
{
    const int idx = blockIdx.x * 256 + threadIdx.x;
    if (idx >= total) return;
    const int co = idx / K, k = idx - co * K;
    o[idx] = f2bf(w[(size_t)co * stride + k]);
}

// ---------------------------------------------------------------------------
// MFMA implicit-GEMM 3x3 conv, split-K over input channels (KS blocks/tile).
// Writes RAW fp32 partials (BN/PReLU in combine).  ROWS rows per block.
// Grid: (64/ROWS, (COUT/COTILE)*KS, 4).  blockIdx.y = ks*(COUT/COTILE)+cob.
// ---------------------------------------------------------------------------
template<int CIN, int COUT, int COTILE, int DIL, int ROWS, int KS>
__global__ __launch_bounds__(256) void conv3x3_mfma(
    const ushort* __restrict__ xin,   // [b][64][64][CIN] bf16
    const ushort* __restrict__ wpk,   // [9][CIN/32][COUT][32] bf16
    float* __restrict__ outp)         // [KS][4][COUT][4096] fp32
{
    constexpr int HR = ROWS + 2 * DIL;
    constexpr int NC = 64 + 2 * DIL;
    constexpr int MT = COTILE / 16;
    constexpr int WPR = 4 / ROWS;
    constexpr int NT = ROWS;
    constexpr int SAS = 40;
    constexpr int NCO = COUT / COTILE;
    constexpr int CH = CIN / 32 / KS;

    const int tid = threadIdx.x;
    const int wave = tid >> 6, lane = tid & 63;
    const int l15 = lane & 15, quad = lane >> 4;
    const int b = blockIdx.z;
    const int cob = blockIdx.y % NCO;
    const int ks = blockIdx.y / NCO;
    const int co0 = cob * COTILE;
    const int h0 = blockIdx.x * ROWS;
    const int row = wave / WPR;
    const int ntbase = (wave % WPR) * NT;

    __shared__ __align__(16) ushort sA[HR * NC * SAS];

    f32x4 acc[MT][NT];
    #pragma unroll
    for (int mt = 0; mt < MT; ++mt)
        #pragma unroll
        for (int nt = 0; nt < NT; ++nt) acc[mt][nt] = (f32x4){0.f, 0.f, 0.f, 0.f};

    #pragma unroll 1
    for (int cc = ks * CH; cc < (ks + 1) * CH; ++cc) {
        __syncthreads();
        constexpr int NA = HR * NC * 4;
        for (int i = tid; i < NA; i += 256) {
            const int p = i >> 2, seg = i & 3;
            const int r = p / NC, c = p - r * NC;
            const int grow = h0 - DIL + r, gcol = c - DIL;
            uint4 val = {0u, 0u, 0u, 0u};
            if (grow >= 0 && grow < 64 && gcol >= 0 && gcol < 64)
                val = *(const uint4*)&xin[((size_t)(b * 64 + grow) * 64 + gcol) * CIN
                                          + cc * 32 + seg * 8];
            *(uint4*)&sA[p * SAS + seg * 8] = val;
        }
        __syncthreads();

        #pragma unroll
        for (int ty = 0; ty < 3; ++ty)
            #pragma unroll
            for (int tx = 0; tx < 3; ++tx) {
                const int tap = ty * 3 + tx;
                bf16x8 aw[MT];
                #pragma unroll
                for (int mt = 0; mt < MT; ++mt)
                    aw[mt] = *(const bf16x8*)&wpk[
                        ((size_t)(tap * (CIN / 32) + cc) * COUT + co0 + mt * 16 + l15) * 32
                        + quad * 8];
                const int rl = row + ty * DIL;
                #pragma unroll
                for (int nt = 0; nt < NT; ++nt) {
                    const int cl = (ntbase + nt) * 16 + l15 + tx * DIL;
                    const bf16x8 bp = *(const bf16x8*)&sA[(rl * NC + cl) * SAS + quad * 8];
                    #pragma unroll
                    for (int mt = 0; mt < MT; ++mt)
                        acc[mt][nt] = __builtin_amdgcn_mfma_f32_16x16x32_bf16(
                            aw[mt], bp, acc[mt][nt], 0, 0, 0);
                }
            }
    }

    #pragma unroll
    for (int mt = 0; mt < MT; ++mt)
        #pragma unroll
        for (int rr = 0; rr < 4; ++rr) {
            const int co = co0 + mt * 16 + quad * 4 + rr;
            #pragma unroll
            for (int nt = 0; nt < NT; ++nt)
                outp[((size_t)((ks * 4 + b) * COUT + co) * 64 + h0 + row) * 64
                     + (ntbase + nt) * 16 + l15] = acc[mt][nt][rr];
        }
}

// ---------------------------------------------------------------------------
// MFMA 1x1 conv on channel-last bf16 input, frags straight from global.
// ---------------------------------------------------------------------------
template<int CIN, int COUT, bool BNACT, int OMODE>
__global__ __launch_bounds__(256) void gemm1x1_cl(
    const ushort* __restrict__ xin,   // [16384][CIN] bf16
    const ushort* __restrict__ wbf,   // [COUT][CIN] bf16
    const float* __restrict__ bias, const float* __restrict__ bng,
    const float* __restrict__ bnb, const float* __restrict__ bnm,
    const float* __restrict__ bnv, const float* __restrict__ al,
    const float* __restrict__ ebias, void* __restrict__ outv,
    int ostride, int ocol)
{
    const int tid = threadIdx.x;
    const int wave = tid >> 6, lane = tid & 63;
    const int l15 = lane & 15, quad = lane >> 4;
    const int pix0 = blockIdx.x * 128 + wave * 32;
    const int co0 = blockIdx.y * 64;

    f32x4 acc[4][2];
    #pragma unroll
    for (int mt = 0; mt < 4; ++mt)
        #pragma unroll
        for (int nt = 0; nt < 2; ++nt) acc[mt][nt] = (f32x4){0.f, 0.f, 0.f, 0.f};

    #pragma unroll 2
    for (int cc = 0; cc < CIN / 32; ++cc) {
        bf16x8 aw[4], bp[2];
        #pragma unroll
        for (int mt = 0; mt < 4; ++mt)
            aw[mt] = *(const bf16x8*)&wbf[(size_t)(co0 + mt * 16 + l15) * CIN + cc * 32 + quad * 8];
        #pragma unroll
        for (int nt = 0; nt < 2; ++nt)
            bp[nt] = *(const bf16x8*)&xin[(size_t)(pix0 + nt * 16 + l15) * CIN + cc * 32 + quad * 8];
        #pragma unroll
        for (int mt = 0; mt < 4; ++mt)
            #pragma unroll
            for (int nt = 0; nt < 2; ++nt)
                acc[mt][nt] = __builtin_amdgcn_mfma_f32_16x16x32_bf16(
                    aw[mt], bp[nt], acc[mt][nt], 0, 0, 0);
    }

    const int bI = pix0 >> 12;
    const float a = BNACT ? al[0] : 0.f;

    if (OMODE == 0) {
        float* out = (float*)outv;
        #pragma unroll
        for (int mt = 0; mt < 4; ++mt)
            #pragma unroll
            for (int r = 0; r < 4; ++r) {
                const int co = co0 + mt * 16 + quad * 4 + r;
                float bb = bias[co];
                if (ebias) bb += ebias[bI * COUT + co];
                float scale = 1.f, shift = bb;
                if (BNACT) {
                    scale = bng[co] * rsqrtf(bnv[co] + EPSV);
                    shift = bb * scale + (bnb[co] - bnm[co] * scale);
                }
                #pragma unroll
                for (int nt = 0; nt < 2; ++nt) {
                    float t = acc[mt][nt][r] * scale + shift;
                    if (BNACT) t = t >= 0.f ? t : a * t;
                    out[((size_t)(bI * COUT + co)) * HW + (pix0 & 4095) + nt * 16 + l15] = t;
                }
            }
    } else {
        __shared__ ushort sT[4][32][68];
        #pragma unroll
        for (int mt = 0; mt < 4; ++mt)
            #pragma unroll
            for (int r = 0; r < 4; ++r) {
                const int co = co0 + mt * 16 + quad * 4 + r;
                float bb = bias[co];
                float scale = 1.f, shift = bb;
                if (BNACT) {
                    scale = bng[co] * rsqrtf(bnv[co] + EPSV);
                    shift = bb * scale + (bnb[co] - bnm[co] * scale);
                }
                #pragma unroll
                for (int nt = 0; nt < 2; ++nt) {
                    float t = acc[mt][nt][r] * scale + shift;
                    if (BNACT) t = t >= 0.f ? t : a * t;
                    sT[wave][nt * 16 + l15][mt * 16 + quad * 4 + r] = f2bf(t);
                }
            }
        __syncthreads();
        const int p = lane >> 1, half = lane & 1;
        ushort* out = (ushort*)outv;
        #pragma unroll
        for (int seg = 0; seg < 4; ++seg) {
            uint2 a0 = *(uint2*)&sT[wave][p][half * 32 + seg * 8];
            uint2 a1 = *(uint2*)&sT[wave][p][half * 32 + seg * 8 + 4];
            uint4 vv = {a0.x, a0.y, a1.x, a1.y};
            *(uint4*)&out[(size_t)(pix0 + p) * ostride + ocol + co0 + half * 32 + seg * 8] = vv;
        }
    }
}

// ---------------------------------------------------------------------------
// Generic fp32 1x1 conv (kept for v).  OUTBF16: write bf16.
// ---------------------------------------------------------------------------
template<int CIN, bool BNACT, bool OUTBF16>
__global__ __launch_bounds__(256) void conv1x1_kernel(
    const float* __restrict__ in0,
    const float* __restrict__ wgt, int wstride, int COUT,
    const float* __restrict__ bias, const float* __restrict__ al,
    void* __restrict__ outv)
{
    const int tid = threadIdx.x;
    const int b = blockIdx.z, co0 = blockIdx.y * 64, p0 = blockIdx.x * 64;
    const int cg = tid >> 4, pg = tid & 15;
    const int c0l = cg * 4, w0 = pg * 4;

    __shared__ __align__(16) float sIn[16 * 64];
    __shared__ __align__(16) float sW[16 * 68];

    float acc[4][4] = {};

    for (int cc = 0; cc < CIN; cc += 16) {
        {
            int i = tid;
            #pragma unroll
            for (int it = 0; it < 4; ++it, i += 256) {
                const int px = i & 63, ci = i >> 6;
                sIn[ci * 64 + px] = in0[(size_t)(b * CIN + cc + ci) * HW + p0 + px];
            }
            i = tid;
            #pragma unroll
            for (int it = 0; it < 4; ++it, i += 256) {
                const int ci = i & 15, co = i >> 4;
                sW[ci * 68 + co] = wgt[(co0 + co) * wstride + cc + ci];
            }
        }
        __syncthreads();
        #pragma unroll
        for (int ci = 0; ci < 16; ++ci) {
            const float4 iv = *(const float4*)&sIn[ci * 64 + w0];
            const float4 wv = *(const float4*)&sW[ci * 68 + c0l];
            const float ia[4] = {iv.x, iv.y, iv.z, iv.w};
            const float wa[4] = {wv.x, wv.y, wv.z, wv.w};
            #pragma unroll
            for (int i2 = 0; i2 < 4; ++i2)
                #pragma unroll
                for (int j = 0; j < 4; ++j)
                    acc[i2][j] = fmaf(wa[i2], ia[j], acc[i2][j]);
        }
        __syncthreads();
    }

    const float a = BNACT ? al[0] : 0.f;
    #pragma unroll
    for (int i2 = 0; i2 < 4; ++i2) {
        const int co = co0 + c0l + i2;
        const float shift = bias[co];
        float r[4];
        #pragma unroll
        for (int j = 0; j < 4; ++j) {
            float t = acc[i2][j] + shift;
            r[j] = (BNACT && t < 0.f) ? a * t : t;
        }
        const size_t base = (size_t)(b * COUT + co) * HW + p0 + w0;
        if (OUTBF16) {
            ushort* out = (ushort*)outv;
            #pragma unroll
            for (int j = 0; j < 4; ++j) out[base + j] = f2bf(r[j]);
        } else {
            float* out = (float*)outv;
            *(float4*)&out[base] = make_float4(r[0], r[1], r[2], r[3]);
        }
    }
}

// ---------------------------------------------------------------------------
// q & k 1x1 convs (128 -> 16 each) -> packed bf16 [b][4096][32]
// ---------------------------------------------------------------------------
__global__ __launch_bounds__(256) void qk_kernel(
    const float* __restrict__ c2g, const float* __restrict__ qw,
    const float* __restrict__ qb2, const float* __restrict__ kw,
    const float* __restrict__ kb2, ushort* __restrict__ qpack,
    ushort* __restrict__ kpack)
{
    const int b = blockIdx.y, p0 = blockIdx.x * 64, tid = threadIdx.x;
    __shared__ float sC[128][64];
    __shared__ float sWq[16][128];
    __shared__ float sWk[16][128];
    for (int i = tid; i < 8192; i += 256) {
        const int px = i & 63, ci = i >> 6;
        sC[ci][px] = c2g[(size_t)(b * 128 + ci) * HW + p0 + px];
    }
    for (int i = tid; i < 2048; i += 256) {
        const int ci = i & 127, co = i >> 7;
        sWq[co][ci] = qw[co * 128 + ci];
        sWk[co][ci] = kw[co * 128 + ci];
    }
    __syncthreads();
    const int px = tid & 63, grp = tid >> 6;
    const int co0 = (grp & 1) * 8;
    const bool isK = grp >= 2;
    const float* sWp = isK ? &sWk[0][0] : &sWq[0][0];
    float acc[8] = {};
    for (int ci = 0; ci < 128; ++ci) {
        const float xv = sC[ci][px];
        #pragma unroll
        for (int j = 0; j < 8; ++j)
            acc[j] = fmaf(sWp[(co0 + j) * 128 + ci], xv, acc[j]);
    }
    const float* bsrc = isK ? kb2 : qb2;
    ushort* osrc = isK ? kpack : qpack;
    const size_t base = (size_t)(b * 4096 + p0 + px) * 32;
    #pragma unroll
    for (int j = 0; j < 8; ++j) {
        osrc[base + co0 + j] = f2bf(acc[j] + bsrc[co0 + j]);
        osrc[base + 16 + co0 + j] = 0;
    }
}

// ---------------------------------------------------------------------------
// Two-pass flash attention, V staged through block-shared LDS.
// Grid: (32 nblk, 8 msplit, 4 batch).
// ---------------------------------------------------------------------------
__global__ __launch_bounds__(256) void attn_flash(
    const ushort* __restrict__ qpack,
    const ushort* __restrict__ kpack,
    const ushort* __restrict__ vpackT,
    ushort* __restrict__ opart,       // [b][8j][4096n][128c] bf16
    float* __restrict__ Mpart,        // [b][8j][4096n]
    float* __restrict__ Spart)
{
    const int tid = threadIdx.x;
    const int wave = tid >> 6, lane = tid & 63;
    const int l15 = lane & 15, quad = lane >> 4;
    const int b = blockIdx.z, j = blockIdx.y;
    const int n0w = blockIdx.x * 128 + wave * 32;
    const int m_begin = j * 512;

    __shared__ __align__(16) ushort sV[2][128][40];
    __shared__ __align__(16) ushort sP[4][2][16][40];

    const bf16x8 bq0 = *(const bf16x8*)(qpack + ((size_t)(b * 4096 + n0w + l15) * 32 + quad * 8));
    const bf16x8 bq1 = *(const bf16x8*)(qpack + ((size_t)(b * 4096 + n0w + 16 + l15) * 32 + quad * 8));
    const f32x4 z = {0.f, 0.f, 0.f, 0.f};

    float runM0 = -3e30f, runM1 = -3e30f;
    #pragma unroll 2
    for (int t = 0; t < 8; ++t) {
        const int m0 = m_begin + t * 64;
        #pragma unroll
        for (int ms = 0; ms < 4; ++ms) {
            const bf16x8 ak = *(const bf16x8*)(
                kpack + ((size_t)(b * 4096 + m0 + ms * 16 + l15) * 32 + quad * 8));
            const f32x4 s0 = __builtin_amdgcn_mfma_f32_16x16x32_bf16(ak, bq0, z, 0, 0, 0);
            const f32x4 s1 = __builtin_amdgcn_mfma_f32_16x16x32_bf16(ak, bq1, z, 0, 0, 0);
            runM0 = fmaxf(runM0, fmaxf(fmaxf(s0[0], s0[1]), fmaxf(s0[2], s0[3])));
            runM1 = fmaxf(runM1, fmaxf(fmaxf(s1[0], s1[1]), fmaxf(s1[2], s1[3])));
        }
    }
    runM0 = fmaxf(runM0, __shfl_xor(runM0, 16));
    runM0 = fmaxf(runM0, __shfl_xor(runM0, 32));
    runM1 = fmaxf(runM1, __shfl_xor(runM1, 16));
    runM1 = fmaxf(runM1, __shfl_xor(runM1, 32));
    const float Ms0 = runM0 * 1.44269504f;
    const float Ms1 = runM1 * 1.44269504f;

    float runS0 = 0.f, runS1 = 0.f;
    f32x4 oacc0[8], oacc1[8];
    #pragma unroll
    for (int cs = 0; cs < 8; ++cs) {
        oacc0[cs] = (f32x4){0.f, 0.f, 0.f, 0.f};
        oacc1[cs] = (f32x4){0.f, 0.f, 0.f, 0.f};
    }

    const int stc = tid >> 1, stseg = tid & 1;

    {
        uint4 v0 = *(const uint4*)&vpackT[(size_t)(b * 128 + stc) * HW + m_begin + stseg * 16];
        uint4 v1 = *(const uint4*)&vpackT[(size_t)(b * 128 + stc) * HW + m_begin + stseg * 16 + 8];
        *(uint4*)&sV[0][stc][stseg * 16] = v0;
        *(uint4*)&sV[0][stc][stseg * 16 + 8] = v1;
    }
    __syncthreads();

    #pragma unroll 1
    for (int t = 0; t < 16; ++t) {
        const int m0 = m_begin + t * 32;
        const int buf = t & 1;
        uint4 nv0, nv1;
        const bool more = (t + 1 < 16);
        if (more) {
            const size_t nb = (size_t)(b * 128 + stc) * HW + m0 + 32 + stseg * 16;
            nv0 = *(const uint4*)&vpackT[nb];
            nv1 = *(const uint4*)&vpackT[nb + 8];
        }
        f32x4 s0[2], s1[2];
        #pragma unroll
        for (int ms = 0; ms < 2; ++ms) {
            const bf16x8 ak = *(const bf16x8*)(
                kpack + ((size_t)(b * 4096 + m0 + ms * 16 + l15) * 32 + quad * 8));
            s0[ms] = __builtin_amdgcn_mfma_f32_16x16x32_bf16(ak, bq0, z, 0, 0, 0);
            s1[ms] = __builtin_amdgcn_mfma_f32_16x16x32_bf16(ak, bq1, z, 0, 0, 0);
        }
        #pragma unroll
        for (int ms = 0; ms < 2; ++ms) {
            float p0[4], p1[4];
            #pragma unroll
            for (int r = 0; r < 4; ++r) {
                p0[r] = __builtin_amdgcn_exp2f(fmaf(s0[ms][r], 1.44269504f, -Ms0));
                p1[r] = __builtin_amdgcn_exp2f(fmaf(s1[ms][r], 1.44269504f, -Ms1));
                runS0 += p0[r];
                runS1 += p1[r];
            }
            ushort4 u0, u1;
            u0.x = f2bf(p0[0]); u0.y = f2bf(p0[1]); u0.z = f2bf(p0[2]); u0.w = f2bf(p0[3]);
            u1.x = f2bf(p1[0]); u1.y = f2bf(p1[1]); u1.z = f2bf(p1[2]); u1.w = f2bf(p1[3]);
            *(uint2*)&sP[wave][0][l15][ms * 16 + quad * 4] = *(uint2*)&u0;
            *(uint2*)&sP[wave][1][l15][ms * 16 + quad * 4] = *(uint2*)&u1;
        }
        asm volatile("s_waitcnt lgkmcnt(0)" ::: "memory");
        const bf16x8 ap0 = *(const bf16x8*)&sP[wave][0][l15][quad * 8];
        const bf16x8 ap1 = *(const bf16x8*)&sP[wave][1][l15][quad * 8];
        #pragma unroll
        for (int cs = 0; cs < 8; ++cs) {
            const bf16x8 bv = *(const bf16x8*)&sV[buf][cs * 16 + l15][quad * 8];
            oacc0[cs] = __builtin_amdgcn_mfma_f32_16x16x32_bf16(ap0, bv, oacc0[cs], 0, 0, 0);
            oacc1[cs] = __builtin_amdgcn_mfma_f32_16x16x32_bf16(ap1, bv, oacc1[cs], 0, 0, 0);
        }
        if (more) {
            *(uint4*)&sV[buf ^ 1][stc][stseg * 16] = nv0;
            *(uint4*)&sV[buf ^ 1][stc][stseg * 16 + 8] = nv1;
            __syncthreads();
        }
    }

    runS0 += __shfl_xor(runS0, 16);
    runS0 += __shfl_xor(runS0, 32);
    runS1 += __shfl_xor(runS1, 16);
    runS1 += __shfl_xor(runS1, 32);
    if (lane < 32) {
        const float Mv = (lane < 16) ? runM0 : runM1;
        const float Sv = (lane < 16) ? runS0 : runS1;
        const int n = n0w + ((lane < 16) ? 0 : 16) + l15;
        Mpart[((size_t)b * 8 + j) * 4096 + n] = Mv;
        Spart[((size_t)b * 8 + j) * 4096 + n] = Sv;
    }
    #pragma unroll
    for (int cs = 0; cs < 8; ++cs)
        #pragma unroll
        for (int r = 0; r < 4; ++r) {
            const int n = n0w + quad * 4 + r;
            opart[(((size_t)b * 8 + j) * 4096 + n) * 128 + cs * 16 + l15] = f2bf(oacc0[cs][r]);
            opart[(((size_t)b * 8 + j) * 4096 + n + 16) * 128 + cs * 16 + l15] = f2bf(oacc1[cs][r]);
        }
}

// ---------------------------------------------------------------------------
// Combine 8 m-split partials, normalize, fuse gamma2*O + c2 -> catb[:,128:256]
// ---------------------------------------------------------------------------
__global__ __launch_bounds__(256) void attn_combine(
    const ushort* __restrict__ opart, const float* __restrict__ Mpart,
    const float* __restrict__ Spart, const float* __restrict__ c2g,
    const float* __restrict__ gamma2, ushort* __restrict__ catb)
{
    const int b = blockIdx.y, n0 = blockIdx.x * 32, tid = threadIdx.x;
    __shared__ float sC2[128][33];
    __shared__ float sWj[8][32];
    if (tid < 32) {
        const int n = n0 + tid;
        float Mj[8], Sj[8];
        #pragma unroll
        for (int j = 0; j < 8; ++j) {
            Mj[j] = Mpart[((size_t)b * 8 + j) * 4096 + n];
            Sj[j] = Spart[((size_t)b * 8 + j) * 4096 + n];
        }
        float M = -3e30f;
        #pragma unroll
        for (int j = 0; j < 8; ++j) M = fmaxf(M, Mj[j]);
        float St = 0.f, e[8];
        #pragma unroll
        for (int j = 0; j < 8; ++j) { e[j] = __expf(Mj[j] - M); St += Sj[j] * e[j]; }
        const float inv = 1.0f / St;
        #pragma unroll
        for (int j = 0; j < 8; ++j) sWj[j][tid] = e[j] * inv;
    }
    #pragma unroll
    for (int e = 0; e < 16; ++e) {
        const int idx = tid + e * 256;
        const int c = idx >> 5, n = idx & 31;
        sC2[c][n] = c2g[(size_t)(b * 128 + c) * HW + n0 + n];
    }
    __syncthreads();
    const float g2 = gamma2[0];
    #pragma unroll
    for (int e = 0; e < 16; ++e) {
        const int idx = tid + e * 256;
        const int n = idx >> 7, c = idx & 127;
        float s = 0.f;
        #pragma unroll
        for (int j = 0; j < 8; ++j)
            s += bf2f(opart[(((size_t)b * 8 + j) * 4096 + n0 + n) * 128 + c]) * sWj[j][n];
        catb[(size_t)(b * 4096 + n0 + n) * 256 + 128 + c] = f2bf(fmaf(g2, s, sC2[c][n]));
    }
}

// ---------------------------------------------------------------------------
// Pool over dc partials (BN+PReLU applied inline).
// ---------------------------------------------------------------------------
__global__ __launch_bounds__(256) void pool_kernel(
    const float* __restrict__ part,     // [8][256][4096]
    const float* __restrict__ bias, const float* __restrict__ bng,
    const float* __restrict__ bnb, const float* __restrict__ bnm,
    const float* __restrict__ bnv, const float* __restrict__ al,
    float* __restrict__ pool)
{
    const int c = blockIdx.x, b = blockIdx.y, tid = threadIdx.x;
    const float sc = bng[c] * rsqrtf(bnv[c] + EPSV);
    const float sh = (bias[c] - bnm[c]) * sc + bnb[c];
    const float a = al[0];
    const float4* r0 = (const float4*)(part + (size_t)(b * 256 + c) * HW);
    const float4* r1 = (const float4*)(part + (size_t)((4 + b) * 256 + c) * HW);
    float s = 0.f;
    #pragma unroll 4
    for (int i = tid; i < 1024; i += 256) {
        const float4 t0 = r0[i];
        const float4 t1 = r1[i];
        float v, t;
        v = t0.x + t1.x; t = v * sc + sh; s += t >= 0.f ? t : a * t;
        v = t0.y + t1.y; t = v * sc + sh; s += t >= 0.f ? t : a * t;
        v = t0.z + t1.z; t = v * sc + sh; s += t >= 0.f ? t : a * t;
        v = t0.w + t1.w; t = v * sc + sh; s += t >= 0.f ? t : a * t;
    }
    __shared__ float red[256];
    red[tid] = s; __syncthreads();
    for (int st = 128; st > 0; st >>= 1) {
        if (tid < st) red[tid] += red[tid + st];
        __syncthreads();
    }
    if (tid == 0) pool[b * 256 + c] = red[0] * (1.0f / 4096.0f);
}

// ---------------------------------------------------------------------------
__global__ __launch_bounds__(256) void c3_fbias_kernel(
    const float* __restrict__ pool, const float* __restrict__ c3w,
    const float* __restrict__ c3b, const float* __restrict__ bng,
    const float* __restrict__ bnb, const float* __restrict__ bnm,
    const float* __restrict__ bnv, const float* __restrict__ al,
    const float* __restrict__ fw, float* __restrict__ fbias)
{
    const int b = blockIdx.x, tid = threadIdx.x;
    __shared__ float sp[256];
    __shared__ float sc3[128];
    sp[tid] = pool[b * 256 + tid];
    __syncthreads();
    if (tid < 128) {
        float acc = c3b[tid];
        for (int ci = 0; ci < 256; ++ci) acc = fmaf(c3w[tid * 256 + ci], sp[ci], acc);
        const float scale = bng[tid] * rsqrtf(bnv[tid] + EPSV);
        float t = (acc - bnm[tid]) * scale + bnb[tid];
        const float a = al[0];
        sc3[tid] = t >= 0.f ? t : a * t;
    }
    __syncthreads();
    float f = 0.f;
    for (int j = 0; j < 128; ++j) f = fmaf(fw[tid * 384 + 256 + j], sc3[j], f);
    fbias[b * 256 + tid] = f;
}

// ---------------------------------------------------------------------------
extern "C" void kernel_launch(void* const* d_in, const int* in_sizes, int n_in,
                              void* d_out, int out_size, void* d_ws, size_t ws_size,
                              hipStream_t stream)
{
    const float* x     = (const float*)d_in[0];
    const float* dc_w  = (const float*)d_in[1];
    const float* dc_b  = (const float*)d_in[2];
    const float* dc_g  = (const float*)d_in[3];
    const float* dc_bt = (const float*)d_in[4];
    const float* dc_m  = (const float*)d_in[5];
    const float* dc_v  = (const float*)d_in[6];
    const float* dc_a  = (const float*)d_in[7];
    const float* c1_w  = (const float*)d_in[8];
    const float* c1_b  = (const float*)d_in[9];
    const float* c1_g  = (const float*)d_in[10];
    const float* c1_bt = (const float*)d_in[11];
    const float* c1_m  = (const float*)d_in[12];
    const float* c1_v  = (const float*)d_in[13];
    const float* c1_a  = (const float*)d_in[14];
    const float* c2_w  = (const float*)d_in[15];
    const float* c2_b  = (const float*)d_in[16];
    const float* c2_g  = (const float*)d_in[17];
    const float* c2_bt = (const float*)d_in[18];
    const float* c2_m  = (const float*)d_in[19];
    const float* c2_v  = (const float*)d_in[20];
    const float* c2_a  = (const float*)d_in[21];
    const float* q_w   = (const float*)d_in[22];
    const float* q_b   = (const float*)d_in[23];
    const float* k_w   = (const float*)d_in[24];
    const float* k_b   = (const float*)d_in[25];
    const float* v_w   = (const float*)d_in[26];
    const float* v_b   = (const float*)d_in[27];
    const float* gamma2= (const float*)d_in[28];
    const float* c3_w  = (const float*)d_in[29];
    const float* c3_b  = (const float*)d_in[30];
    const float* c3_g  = (const float*)d_in[31];
    const float* c3_bt = (const float*)d_in[32];
    const float* c3_m  = (const float*)d_in[33];
    const float* c3_v  = (const float*)d_in[34];
    const float* c3_a  = (const float*)d_in[35];
    const float* f_w   = (const float*)d_in[36];
    const float* f_b   = (const float*)d_in[37];
    const float* f_g   = (const float*)d_in[38];
    const float* f_bt  = (const float*)d_in[39];
    const float* f_m   = (const float*)d_in[40];
    const float* f_v   = (const float*)d_in[41];
    const float* f_a   = (const float*)d_in[42];

    // ---- workspace layout by live range ----
    char* base = (char*)d_ws;
    ushort* xbf   = (ushort*)base;                       // [4,4096,512] bf16 (steps 0-1)
    float*  dcp   = (float*)(base + 16777216);           // [2][4][256][4096] f32 (1-2)
    ushort* opart = (ushort*)base;                       // [4,8,4096,128] bf16 (attn)
    float*  c2p   = (float*)(base + 33554432);           // [2][4][128][4096] f32 (c2)
    ushort* qpk   = (ushort*)(base + 33554432);          // [4,4096,32] (post c2-combine)
    ushort* kpk   = (ushort*)(base + 34603008);
    ushort* vbh   = (ushort*)(base + 35651584);          // [4,128,4096] bf16
    ushort* xpbf  = (ushort*)(base + 50331648);          // [4,4096,256] bf16 (dc_combine..c2)
    float*  c2b   = (float*)(base + 50331648);           // [4,128,4096] f32 (c2_combine..attn_combine)
    ushort* catb  = (ushort*)(base + 58720256);          // [4,4096,256] bf16
    ushort* wdcp  = (ushort*)(base + 75497472);          // [9,16,256,32]
    ushort* wc2p  = (ushort*)(base + 77856768);          // [9,8,128,32]
    ushort* wc1b  = (ushort*)(base + 78446592);          // [128,256]
    ushort* wfb   = (ushort*)(base + 78512128);          // [256,256]
    float*  poolb = (float*)(base + 78643200);           // 1024
    float*  fbb   = (float*)(base + 78647296);           // 1024
    float*  Mpart = (float*)(base + 78651392);           // [4,8,4096]
    float*  Spart = (float*)(base + 79175680);           // [4,8,4096]

    // 0. packs + x -> channel-last bf16
    pack_w3x3<512, 256><<<dim3((9*16*256*32 + 255)/256), 256, 0, stream>>>(dc_w, wdcp);
    pack_w3x3<256, 128><<<dim3((9*8*128*32 + 255)/256), 256, 0, stream>>>(c2_w, wc2p);
    pack_w1x1<<<dim3((32768 + 255)/256), 256, 0, stream>>>(c1_w, wc1b, 256, 256, 32768);
    pack_w1x1<<<dim3((65536 + 255)/256), 256, 0, stream>>>(f_w, wfb, 256, 384, 65536);
    to_chlast_bf16<512><<<dim3(64, 8, 4), 256, 0, stream>>>(x, xbf);
    // 1. down_conv 3x3 512->256 (MFMA, split-K=2 -> 1024 blocks)
    conv3x3_mfma<512, 256, 64, 1, 2, 2><<<dim3(32, 8, 4), 256, 0, stream>>>(
        xbf, wdcp, dcp);
    // 2. dc combine (+BN+PReLU) -> bf16 ch-last; pool + c3 fbias from partials
    dc_combine<<<dim3(64, 4, 4), 256, 0, stream>>>(
        dcp, dc_b, dc_g, dc_bt, dc_m, dc_v, dc_a, xpbf);
    pool_kernel<<<dim3(256, 4), 256, 0, stream>>>(
        dcp, dc_b, dc_g, dc_bt, dc_m, dc_v, dc_a, poolb);
    c3_fbias_kernel<<<dim3(4), 256, 0, stream>>>(
        poolb, c3_w, c3_b, c3_g, c3_bt, c3_m, c3_v, c3_a, f_w, fbb);
    // 3. branch1 1x1 (MFMA) -> catb cols 0..127
    gemm1x1_cl<256, 128, true, 1><<<dim3(128, 2), 256, 0, stream>>>(
        xpbf, wc1b, c1_b, c1_g, c1_bt, c1_m, c1_v, c1_a, nullptr, catb, 256, 0);
    // 4. branch2 dilated 3x3 (MFMA, split-K=2 -> 1024 blocks) + combine
    conv3x3_mfma<256, 128, 32, 2, 2, 2><<<dim3(32, 8, 4), 256, 0, stream>>>(
        xpbf, wc2p, c2p);
    c2_combine<<<dim3(4, 128, 4), 256, 0, stream>>>(
        c2p, c2_b, c2_g, c2_bt, c2_m, c2_v, c2_a, c2b);
    // 5. q,k
    qk_kernel<<<dim3(64, 4), 256, 0, stream>>>(c2b, q_w, q_b, k_w, k_b, qpk, kpk);
    // 6. v -> bf16 [c][m]
    conv1x1_kernel<128, false, true><<<dim3(64, 2, 4), 256, 0, stream>>>(
        c2b, v_w, 128, 128, v_b, nullptr, vbh);
    // 7. flash attention (V via LDS) + combine
    attn_flash<<<dim3(32, 8, 4), 256, 0, stream>>>(qpk, kpk, vbh, opart, Mpart, Spart);
    attn_combine<<<dim3(128, 4), 256, 0, stream>>>(opart, Mpart, Spart, c2b, gamma2, catb);
    // 8. fuse conv (MFMA, K=256) -> d_out
    gemm1x1_cl<256, 256, true, 0><<<dim3(128, 4), 256, 0, stream>>>(
        catb, wfb, f_b, f_g, f_bt, f_m, f_v, f_a, fbb, (float*)d_out, 0, 0);
}